// Round 1
// 81.583 us; speedup vs baseline: 1.0272x; 1.0272x over previous
//
#include <hip/hip_runtime.h>

#define NQ 4
#define DIM 16
#define SPT 4   // samples per thread: amortizes the 81 broadcast ds_read_b128
                // over 20 VALU ops each (LDS slot fully hidden) and halves the
                // redundant per-block setup (1024 blocks instead of 2048).

struct cplx { float r, i; };
__device__ inline cplx cmul(cplx a, cplx b) { return {a.r*b.r - a.i*b.i, a.r*b.i + a.i*b.r}; }
__device__ inline cplx cadd(cplx a, cplx b) { return {a.r + b.r, a.i + b.i}; }

// t[9] = (1, cos v, sin v, cos u, cu*cv, cu*sv, sin u, su*cv, su*sv)
__device__ inline void build9(float u, float v, float* t) {
    float su, cu, sv, cv;
    __sincosf(u, &su, &cu);
    __sincosf(v, &sv, &cv);
    t[0] = 1.f;      t[1] = cv;      t[2] = sv;
    t[3] = cu;       t[4] = cu * cv; t[5] = cu * sv;
    t[6] = su;       t[7] = su * cv; t[8] = su * sv;
}

// Fully fused: every block redundantly builds the 324 trig-basis coefficients in
// its own LDS, then runs the per-sample contraction. Removes the setup dispatch,
// its launch gap, and the coef global round-trip.
//
//   out_w = sum_{e in {1,cos,sin}^4} K_w[e] * prod_q f_{e_q}(x_q)
//   K_w[e] = (1/16) sum_b A_w[b][b^m] * parity(b & d1)   (m=sin-bits, d1=cos-bits)
//   A_w[j][k] = sum_idx sign_w(idx) * (Ur[idx][j]Ur[idx][k] + Ui[idx][j]Ui[idx][k])
__global__ __launch_bounds__(256) void qsim_kernel(const float4* __restrict__ x,
                                                   const float* __restrict__ wt,
                                                   float4* __restrict__ out, int quarter) {
    __shared__ float Ur[DIM][DIM];
    __shared__ float Ui[DIM][DIM];
    __shared__ float A[4][DIM][DIM];
    __shared__ float4 lk[81];

    int tid = blockIdx.x * blockDim.x + threadIdx.x;
    bool valid = tid < quarter;
    // Issue input loads first — HBM latency hides behind the setup phases.
    float4 xs[SPT];
#pragma unroll
    for (int s = 0; s < SPT; ++s)
        xs[s] = valid ? x[tid + s * quarter] : make_float4(0.f, 0.f, 0.f, 0.f);

    // ---- Phase 1: evolve basis columns through the shared circuit (16 lanes) ----
    int col = threadIdx.x;
    if (col < DIM) {
        float ar[DIM], ai[DIM];
#pragma unroll
        for (int i = 0; i < DIM; ++i) { ar[i] = 0.f; ai[i] = 0.f; }
        ar[col] = 1.f;
        for (int l = 0; l < 2; ++l) {
            for (int q = 0; q < NQ; ++q) {
                float tx = wt[(l * 4 + q) * 3 + 0];
                float ty = wt[(l * 4 + q) * 3 + 1];
                float tz = wt[(l * 4 + q) * 3 + 2];
                float cx, sx, cy, sy, cz, sz;
                __sincosf(0.5f * tx, &sx, &cx);
                __sincosf(0.5f * ty, &sy, &cy);
                __sincosf(0.5f * tz, &sz, &cz);
                cplx Rx[2][2] = {{{cx, 0.f}, {0.f, -sx}}, {{0.f, -sx}, {cx, 0.f}}};
                cplx Ry[2][2] = {{{cy, 0.f}, {-sy, 0.f}}, {{sy, 0.f}, {cy, 0.f}}};
                cplx Rz[2][2] = {{{cz, -sz}, {0.f, 0.f}}, {{0.f, 0.f}, {cz, sz}}};
                cplx T[2][2], G[2][2];
#pragma unroll
                for (int r = 0; r < 2; ++r)
#pragma unroll
                    for (int c = 0; c < 2; ++c)
                        T[r][c] = cadd(cmul(Ry[r][0], Rx[0][c]), cmul(Ry[r][1], Rx[1][c]));
#pragma unroll
                for (int r = 0; r < 2; ++r)
#pragma unroll
                    for (int c = 0; c < 2; ++c)
                        G[r][c] = cadd(cmul(Rz[r][0], T[0][c]), cmul(Rz[r][1], T[1][c]));
                int pos = 3 - q, mask = 1 << pos;
#pragma unroll
                for (int idx = 0; idx < DIM; ++idx) {
                    if (idx & mask) continue;
                    int i1 = idx | mask;
                    cplx a0 = {ar[idx], ai[idx]}, a1 = {ar[i1], ai[i1]};
                    cplx n0 = cadd(cmul(G[0][0], a0), cmul(G[0][1], a1));
                    cplx n1 = cadd(cmul(G[1][0], a0), cmul(G[1][1], a1));
                    ar[idx] = n0.r; ai[idx] = n0.i;
                    ar[i1] = n1.r;  ai[i1] = n1.i;
                }
            }
            for (int q = 0; q < NQ; ++q) {
                int cpos = 3 - q, tpos = 3 - ((q + 1) & 3);
                int tmask = 1 << tpos;
#pragma unroll
                for (int idx = 0; idx < DIM; ++idx) {
                    if (((idx >> cpos) & 1) && !((idx >> tpos) & 1)) {
                        int i1 = idx | tmask;
                        float tr = ar[idx]; ar[idx] = ar[i1]; ar[i1] = tr;
                        float ti = ai[idx]; ai[idx] = ai[i1]; ai[i1] = ti;
                    }
                }
            }
        }
        for (int i = 0; i < DIM; ++i) { Ur[i][col] = ar[i]; Ui[i][col] = ai[i]; }
    }
    __syncthreads();

    // ---- Phase 2: A_w[j][k], one (j,k) per thread, 4 outputs share products ----
    {
        int j = threadIdx.x >> 4, k = threadIdx.x & 15;
        float a0 = 0.f, a1 = 0.f, a2 = 0.f, a3 = 0.f;
#pragma unroll
        for (int idx = 0; idx < DIM; ++idx) {
            float rr = Ur[idx][j] * Ur[idx][k] + Ui[idx][j] * Ui[idx][k];
            a0 += (idx & 8) ? -rr : rr;
            a1 += (idx & 4) ? -rr : rr;
            a2 += (idx & 2) ? -rr : rr;
            a3 += (idx & 1) ? -rr : rr;
        }
        A[0][j][k] = a0; A[1][j][k] = a1; A[2][j][k] = a2; A[3][j][k] = a3;
    }
    __syncthreads();

    // ---- Phase 3: K transform, 324 scalars into lk (grid-stride: 324 > 256!) ----
    for (int id = threadIdx.x; id < 4 * 81; id += blockDim.x) {
        int w = id & 3, u = id >> 2;
        int e0 = u / 27, e1 = (u / 9) % 3, e2 = (u / 3) % 3, e3 = u % 3;
        int m  = ((e0 == 2) ? 8 : 0) | ((e1 == 2) ? 4 : 0) | ((e2 == 2) ? 2 : 0) | ((e3 == 2) ? 1 : 0);
        int d1 = ((e0 == 1) ? 8 : 0) | ((e1 == 1) ? 4 : 0) | ((e2 == 1) ? 2 : 0) | ((e3 == 1) ? 1 : 0);
        float acc = 0.f;
#pragma unroll
        for (int b = 0; b < DIM; ++b) {
            float sgn = (__popc(b & d1) & 1) ? -1.f : 1.f;
            acc += sgn * A[w][b][b ^ m];
        }
        ((float*)lk)[u * 4 + w] = 0.0625f * acc;
    }
    __syncthreads();

    // ---- Phase 4: per-sample contraction (SPT samples/thread, coalesced) ----
    if (!valid) return;
    float t9[SPT][9], u9[SPT][9];
#pragma unroll
    for (int s = 0; s < SPT; ++s) {
        build9(xs[s].x, xs[s].y, t9[s]);
        build9(xs[s].z, xs[s].w, u9[s]);
    }

    float4 acc[SPT];
#pragma unroll
    for (int s = 0; s < SPT; ++s) acc[s] = make_float4(0.f, 0.f, 0.f, 0.f);

#pragma unroll
    for (int i = 0; i < 9; ++i) {
#pragma unroll
        for (int j = 0; j < 9; ++j) {
            float4 c = lk[i * 9 + j];   // ds_read_b128, imm offset, broadcast
#pragma unroll
            for (int s = 0; s < SPT; ++s) {
                float p = t9[s][i] * u9[s][j];
                acc[s].x = fmaf(c.x, p, acc[s].x);
                acc[s].y = fmaf(c.y, p, acc[s].y);
                acc[s].z = fmaf(c.z, p, acc[s].z);
                acc[s].w = fmaf(c.w, p, acc[s].w);
            }
        }
    }
#pragma unroll
    for (int s = 0; s < SPT; ++s)
        out[tid + s * quarter] = acc[s];
}

extern "C" void kernel_launch(void* const* d_in, const int* in_sizes, int n_in,
                              void* d_out, int out_size, void* d_ws, size_t ws_size,
                              hipStream_t stream) {
    const float* x = (const float*)d_in[0];
    const float* wt = (const float*)d_in[1];
    float* out = (float*)d_out;
    (void)d_ws; (void)ws_size;

    int B = in_sizes[0] / NQ;     // 2^20 samples
    int quarter = B / SPT;        // 4 samples per thread
    int blocks = (quarter + 255) / 256;   // 1024 blocks = 4/CU
    qsim_kernel<<<blocks, 256, 0, stream>>>((const float4*)x, wt, (float4*)out, quarter);
}